// Round 1
// baseline (152.999 us; speedup 1.0000x reference)
//
#include <hip/hip_runtime.h>
#include <math.h>

#define NB 2048
#define DEPTH 8
#define BDEPTH 10
#define BFDEPTH 12

// cos/sin table sizes (in angle count)
#define N_SPONGE_CS (DEPTH * BDEPTH * 512)   // 40960
#define N_BF_CS     (BFDEPTH * 1536)         // 18432

__global__ void cs_precompute(const float* __restrict__ angles,
                              const float* __restrict__ bf_angles,
                              float* __restrict__ tab) {
    int i = blockIdx.x * 256 + threadIdx.x;
    float a;
    if (i < N_SPONGE_CS)                a = angles[i];
    else if (i < N_SPONGE_CS + N_BF_CS) a = bf_angles[i - N_SPONGE_CS];
    else return;
    float s, c;
    sincosf(a, &s, &c);
    tab[2 * i]     = c;
    tab[2 * i + 1] = s;
}

__device__ __forceinline__ float base_act(float x, float c, float ic, float tt,
                                          float y0, float y1) {
    // f(x) = x>t ? y0 + (x-t) : (x<-t ? y1 : (1/c)(1/sqrt2 - cos(pi/4 + c x)))
    float mid = ic * (0.70710678118654752f - __cosf(0.78539816339744831f + c * x));
    return x > tt ? (y0 + (x - tt)) : (x < -tt ? y1 : mid);
}

__launch_bounds__(256)
__global__ void sponge_kernel(const float* __restrict__ X,
                              const float* __restrict__ scales,
                              const float* __restrict__ act_bias,
                              const float* __restrict__ act_curv,
                              const int*   __restrict__ recall_idx,
                              const int*   __restrict__ out_mem_idx,
                              const float* __restrict__ tab,
                              float*       __restrict__ out) {
    __shared__ float lds[8192];          // 32 KB
    float* memb = lds;                   // [0,4096)   mem
    float* bufA = lds + 4096;            // [4096,7168) 3072 floats
    float* bufB = lds + 7168;            // [7168,8192) 1024 floats
    const int t   = threadIdx.x;         // 0..255
    const int row = blockIdx.x;

    // ---- load sponge = X[row]*scales (1024 floats) ----
    {
        float4 xv = ((const float4*)(X + (size_t)row * 1024))[t];
        float4 sv = ((const float4*)scales)[t];
        xv.x *= sv.x; xv.y *= sv.y; xv.z *= sv.z; xv.w *= sv.w;
        ((float4*)bufA)[t] = xv;
    }
    __syncthreads();

    float* cur = bufA;
    float* alt = bufB;
    const float* tb = tab;               // walks the sponge cs table

    for (int d = 0; d < DEPTH; ++d) {
        // ---- 10 butterfly stages, width 1024 ----
        for (int st = 0; st < BDEPTH; ++st) {
            const float4 cs = *(const float4*)(tb + 4 * t);  // (c0,s0,c1,s1) for pairs 2t,2t+1
            tb += 1024;
            float a = cur[t], b = cur[t + 256], c = cur[t + 512], e = cur[t + 768];
            ((float2*)(alt + 2 * t))[0] =
                make_float2( cs.x * a + cs.y * b,  cs.z * c + cs.w * e);
            ((float2*)(alt + 512 + 2 * t))[0] =
                make_float2(-cs.y * a + cs.x * b, -cs.w * c + cs.z * e);
            __syncthreads();
            float* tmp = cur; cur = alt; alt = tmp;
        }
        // ---- repack: mem store, activation, keep, recall ----
        memb[d * 512 + t]       = cur[t];
        memb[d * 512 + 256 + t] = cur[t + 256];
        {
            float x1 = cur[512 + t] + act_bias[d * 256 + t];
            float cu = act_curv[d * 256 + t];
            float c  = 0.5f * (cu + sqrtf(cu * cu + 1.0f));
            float ic = 1.0f / c;
            float tt = 0.78539816339744831f * ic;
            float y0 = 0.70710678118654752f * ic;
            float y1 = (0.70710678118654752f - 1.0f) * ic;
            float ap = base_act( x1, c, ic, tt, y0, y1);
            float am = base_act(-x1, c, ic, tt, y0, y1);
            ((float2*)(alt + 2 * t))[0] = make_float2(ap, am);  // interleave
        }
        alt[512 + t] = cur[768 + t];                 // keep sponge[768:1024]
        __syncthreads();                             // mem writes visible
        alt[768 + t] = memb[recall_idx[d * 256 + t]];
        __syncthreads();
        float* tmp = cur; cur = alt; alt = tmp;
    }

    // ---- build pre = [mem[out_mem_idx] (2048), sponge (1024)] in bufA ----
    float s0 = cur[t], s1 = cur[256 + t], s2 = cur[512 + t], s3 = cur[768 + t];
    __syncthreads();
    bufA[2048 + t]       = s0;
    bufA[2048 + 256 + t] = s1;
    bufA[2048 + 512 + t] = s2;
    bufA[2048 + 768 + t] = s3;
#pragma unroll
    for (int q = 0; q < 8; ++q)
        bufA[q * 256 + t] = memb[out_mem_idx[q * 256 + t]];
    __syncthreads();

    // ---- 12 butterfly stages, width 3072 (ping-pong bufA <-> memb) ----
    cur = bufA; alt = memb;
    const float* bft = tab + 2 * N_SPONGE_CS;
    for (int st = 0; st < BFDEPTH; ++st) {
        const float* tbs = bft + st * 3072;
#pragma unroll
        for (int g = 0; g < 3; ++g) {
            const float4 cs = *(const float4*)(tbs + 4 * t + 1024 * g);
            float a = cur[t + 256 * g];
            float b = cur[t + 256 * g + 768];
            float c = cur[t + 256 * g + 1536];
            float e = cur[t + 256 * g + 2304];
            int j0 = 2 * t + 512 * g;
            ((float2*)(alt + j0))[0] =
                make_float2( cs.x * a + cs.y * b,  cs.z * c + cs.w * e);
            ((float2*)(alt + 1536 + j0))[0] =
                make_float2(-cs.y * a + cs.x * b, -cs.w * c + cs.z * e);
        }
        __syncthreads();
        float* tmp = cur; cur = alt; alt = tmp;
    }

    // ---- output: first 512 of final vector ----
    ((float2*)(out + (size_t)row * 512))[t] = ((const float2*)cur)[t];
}

extern "C" void kernel_launch(void* const* d_in, const int* in_sizes, int n_in,
                              void* d_out, int out_size, void* d_ws, size_t ws_size,
                              hipStream_t stream) {
    const float* X          = (const float*)d_in[0];
    const float* scales     = (const float*)d_in[1];
    const float* angles     = (const float*)d_in[2];
    const float* act_bias   = (const float*)d_in[3];
    // d_in[4] act_activation — unused by the reference
    const float* act_curv   = (const float*)d_in[5];
    const float* bf_angles  = (const float*)d_in[6];
    // d_in[7] shuffle_perm — structural perfect shuffle, hardcoded
    const int*   recall_idx = (const int*)d_in[8];
    const int*   out_mem_idx= (const int*)d_in[9];
    // d_in[10] bf_perm — structural perfect shuffle, hardcoded
    float* tab = (float*)d_ws;   // 2*(40960+18432)*4 = 475136 bytes

    int total = N_SPONGE_CS + N_BF_CS;
    cs_precompute<<<(total + 255) / 256, 256, 0, stream>>>(angles, bf_angles, tab);
    sponge_kernel<<<NB, 256, 0, stream>>>(X, scales, act_bias, act_curv,
                                          recall_idx, out_mem_idx, tab,
                                          (float*)d_out);
}

// Round 2
// 133.490 us; speedup vs baseline: 1.1461x; 1.1461x over previous
//
#include <hip/hip_runtime.h>
#include <hip/hip_bf16.h>
#include <math.h>

#define NB 2048
#define DEPTH 8
#define BDEPTH 10
#define BFDEPTH 12

// cos/sin table sizes (in angle count)
#define N_SPONGE_CS (DEPTH * BDEPTH * 512)   // 40960
#define N_BF_CS     (BFDEPTH * 1536)         // 18432
#define TAB_FLOATS  (2 * (N_SPONGE_CS + N_BF_CS))   // 118784 floats = 475136 B
#define MEM_FLOATS_PER_ROW 4096

__global__ void cs_precompute(const float* __restrict__ angles,
                              const float* __restrict__ bf_angles,
                              float* __restrict__ tab) {
    int i = blockIdx.x * 256 + threadIdx.x;
    float a;
    if (i < N_SPONGE_CS)                a = angles[i];
    else if (i < N_SPONGE_CS + N_BF_CS) a = bf_angles[i - N_SPONGE_CS];
    else return;
    float s, c;
    sincosf(a, &s, &c);
    tab[2 * i]     = c;
    tab[2 * i + 1] = s;
}

__device__ __forceinline__ float base_act(float x, float c, float ic, float tt,
                                          float y0, float y1) {
    float mid = ic * (0.70710678118654752f - __cosf(0.78539816339744831f + c * x));
    return x > tt ? (y0 + (x - tt)) : (x < -tt ? y1 : mid);
}

// MEM_LDS = 0: mem lives in global scratch (f32, exact)
// MEM_LDS = 1: mem lives in LDS as bf16 (fallback if ws too small)
template <int MEM_LDS>
__launch_bounds__(256, 8)
__global__ void sponge_kernel(const float* __restrict__ X,
                              const float* __restrict__ scales,
                              const float* __restrict__ act_bias,
                              const float* __restrict__ act_curv,
                              const int*   __restrict__ recall_idx,
                              const int*   __restrict__ out_mem_idx,
                              const float* __restrict__ tab,
                              float*       __restrict__ gmem,
                              float*       __restrict__ out) {
    __shared__ float buf[3072];                                   // 12 KB
    __shared__ __hip_bfloat16 memb[MEM_LDS ? 4096 : 2];           // 8 KB if used
    const int t   = threadIdx.x;   // 0..255
    const int row = blockIdx.x;
    float* g = gmem + (size_t)row * MEM_FLOATS_PER_ROW;

    // ---- load sponge = X[row]*scales into buf[0:1024) ----
    {
        float4 xv = ((const float4*)(X + (size_t)row * 1024))[t];
        float4 sv = ((const float4*)scales)[t];
        ((float4*)buf)[t] = make_float4(xv.x * sv.x, xv.y * sv.y,
                                        xv.z * sv.z, xv.w * sv.w);
    }
    __syncthreads();

    float* cur = buf;
    float* alt = buf + 1024;
    const float* tb = tab;

    for (int d = 0; d < DEPTH; ++d) {
        // ---- 10 butterfly stages, width 1024, ping-pong, 1 barrier each ----
        for (int st = 0; st < BDEPTH; ++st) {
            const float4 cs = *(const float4*)(tb + 4 * t);  // pairs 2t,2t+1
            tb += 1024;
            float a = cur[t], b = cur[t + 256], c = cur[t + 512], e = cur[t + 768];
            ((float2*)(alt + 2 * t))[0] =
                make_float2( cs.x * a + cs.y * b,  cs.z * c + cs.w * e);
            ((float2*)(alt + 512 + 2 * t))[0] =
                make_float2(-cs.y * a + cs.x * b, -cs.w * c + cs.z * e);
            __syncthreads();
            float* tmp = cur; cur = alt; alt = tmp;
        }
        // ---- repack: mem store, activation, keep, recall ----
        int ri = recall_idx[d * 256 + t];       // prefetch index
        {
            float m0 = cur[t], m1 = cur[t + 256];
            if (MEM_LDS) {
                memb[d * 512 + t]       = __float2bfloat16(m0);
                memb[d * 512 + 256 + t] = __float2bfloat16(m1);
            } else {
                g[d * 512 + t]       = m0;
                g[d * 512 + 256 + t] = m1;
            }
        }
        {
            float x1 = cur[512 + t] + act_bias[d * 256 + t];
            float cu = act_curv[d * 256 + t];
            float c  = 0.5f * (cu + sqrtf(cu * cu + 1.0f));
            float ic = 1.0f / c;
            float tt = 0.78539816339744831f * ic;
            float y0 = 0.70710678118654752f * ic;
            float y1 = (0.70710678118654752f - 1.0f) * ic;
            float ap = base_act( x1, c, ic, tt, y0, y1);
            float am = base_act(-x1, c, ic, tt, y0, y1);
            ((float2*)(alt + 2 * t))[0] = make_float2(ap, am);
        }
        alt[512 + t] = cur[768 + t];
        __syncthreads();                         // mem writes visible (LDS & global)
        alt[768 + t] = MEM_LDS ? __bfloat162float(memb[ri]) : g[ri];
        __syncthreads();
        float* tmp = cur; cur = alt; alt = tmp;
    }
    // net swaps per depth = 11 (odd), 8 depths -> cur == buf here.

    // ---- build pre in buf[0:3072): gather mem -> [0,2048), sponge -> [2048,3072) ----
    float s0 = cur[t], s1 = cur[256 + t], s2 = cur[512 + t], s3 = cur[768 + t];
    __syncthreads();
    buf[2048 + t]       = s0;
    buf[2048 + 256 + t] = s1;
    buf[2048 + 512 + t] = s2;
    buf[2048 + 768 + t] = s3;
#pragma unroll
    for (int q = 0; q < 8; ++q) {
        int oi = out_mem_idx[q * 256 + t];
        buf[q * 256 + t] = MEM_LDS ? __bfloat162float(memb[oi]) : g[oi];
    }
    __syncthreads();

    const float* bft = tab + 2 * N_SPONGE_CS;

    // ---- stages 0..2: full 3072-wide, in place (read->sync->write->sync) ----
    for (int s = 0; s < 3; ++s) {
        const float* tbs = bft + s * 3072;
        float  r[12];
        float4 csg[3];
#pragma unroll
        for (int gi = 0; gi < 3; ++gi) {
            csg[gi] = *(const float4*)(tbs + 4 * t + 1024 * gi);
            r[4 * gi + 0] = buf[t + 256 * gi];
            r[4 * gi + 1] = buf[t + 256 * gi + 768];
            r[4 * gi + 2] = buf[t + 256 * gi + 1536];
            r[4 * gi + 3] = buf[t + 256 * gi + 2304];
        }
        __syncthreads();
#pragma unroll
        for (int gi = 0; gi < 3; ++gi) {
            int j0 = 2 * t + 512 * gi;
            float4 cs = csg[gi];
            float a = r[4 * gi], b = r[4 * gi + 1], c = r[4 * gi + 2], e = r[4 * gi + 3];
            ((float2*)(buf + j0))[0] =
                make_float2( cs.x * a + cs.y * b,  cs.z * c + cs.w * e);
            ((float2*)(buf + 1536 + j0))[0] =
                make_float2(-cs.y * a + cs.x * b, -cs.w * c + cs.z * e);
        }
        __syncthreads();
    }

    // ---- stages 3..10: pruned to the 512 needed rotation-pairs ----
    // needed pairs at stage s: { p in [0,1536) : p mod (768>>(10-s)) < (256>>(10-s)) }
#pragma unroll
    for (int s = 3; s < 11; ++s) {
        const float* tbs = bft + s * 3072;
        const int k = 10 - s;          // s=10 -> k=0 ... s=3 -> k=7
        const int M = 768 >> k;
        const int Wl = 8 - k;          // log2(W), W = 256>>k
        const int Wm = (256 >> k) - 1;
        float  X1[2], X2[2];
        float2 cs2[2];
        int    pp[2];
#pragma unroll
        for (int u = 0; u < 2; ++u) {
            int i = t + 256 * u;
            int p = ((i >> Wl) * M) + (i & Wm);
            pp[u]  = p;
            cs2[u] = *(const float2*)(tbs + 2 * p);
            X1[u] = buf[(p >> 1) + (p & 1) * 1536];          // s[p]
            X2[u] = buf[768 + (p >> 1) + (p & 1) * 1536];    // s[p+1536]
        }
        __syncthreads();
#pragma unroll
        for (int u = 0; u < 2; ++u) {
            buf[pp[u]]        =  cs2[u].x * X1[u] + cs2[u].y * X2[u];
            buf[pp[u] + 1536] = -cs2[u].y * X1[u] + cs2[u].x * X2[u];
        }
        __syncthreads();
    }

    // ---- stage 11 fused into the output store: only out[0:512) ----
    {
        const float* tbs = bft + 11 * 3072;
        float4 cs = *(const float4*)(tbs + 4 * t);  // pairs 2t, 2t+1
        float a = buf[t], b = buf[768 + t], c = buf[1536 + t], e = buf[2304 + t];
        ((float2*)(out + (size_t)row * 512))[t] =
            make_float2(cs.x * a + cs.y * b, cs.z * c + cs.w * e);
    }
}

extern "C" void kernel_launch(void* const* d_in, const int* in_sizes, int n_in,
                              void* d_out, int out_size, void* d_ws, size_t ws_size,
                              hipStream_t stream) {
    const float* X          = (const float*)d_in[0];
    const float* scales     = (const float*)d_in[1];
    const float* angles     = (const float*)d_in[2];
    const float* act_bias   = (const float*)d_in[3];
    // d_in[4] act_activation — unused by the reference
    const float* act_curv   = (const float*)d_in[5];
    const float* bf_angles  = (const float*)d_in[6];
    // d_in[7] shuffle_perm — structural perfect shuffle, hardcoded
    const int*   recall_idx  = (const int*)d_in[8];
    const int*   out_mem_idx = (const int*)d_in[9];
    // d_in[10] bf_perm — structural perfect shuffle, hardcoded

    float* tab  = (float*)d_ws;
    float* gmem = (float*)d_ws + TAB_FLOATS;

    int total = N_SPONGE_CS + N_BF_CS;
    cs_precompute<<<(total + 255) / 256, 256, 0, stream>>>(angles, bf_angles, tab);

    size_t need = (size_t)TAB_FLOATS * 4 + (size_t)NB * MEM_FLOATS_PER_ROW * 4;
    if (ws_size >= need) {
        sponge_kernel<0><<<NB, 256, 0, stream>>>(X, scales, act_bias, act_curv,
                                                 recall_idx, out_mem_idx, tab,
                                                 gmem, (float*)d_out);
    } else {
        sponge_kernel<1><<<NB, 256, 0, stream>>>(X, scales, act_bias, act_curv,
                                                 recall_idx, out_mem_idx, tab,
                                                 gmem, (float*)d_out);
    }
}

// Round 3
// 127.017 us; speedup vs baseline: 1.2046x; 1.0510x over previous
//
#include <hip/hip_runtime.h>
#include <math.h>

#define NB 2048
#define DEPTH 8

// ws layout (float offsets)
#define FTAB_OFF   0          // fused sponge cs: 8*5*256*8 = 81920 floats
#define BFT_OFF    81920      // bf cs natural: 12*1536*2 = 36864 floats
#define ACT4_OFF   118784     // act table: 2048 float4 = 8192 floats
#define PHYS_OFF   126976     // phys[4096] int
#define PHYSR_OFF  131072     // phys_recall[2048] int
#define PHYSO_OFF  133120     // phys_out[2048] int
#define WS_FLOATS  135168     // 540672 bytes

// ---------------- precompute: cos/sin tables + activation constants ----------------
__global__ void tab_precompute(const float* __restrict__ angles,
                               const float* __restrict__ bf_angles,
                               const float* __restrict__ act_bias,
                               const float* __restrict__ act_curv,
                               float* __restrict__ ws) {
    int id = blockIdx.x * 256 + threadIdx.x;
    if (id < 40960) {
        // fused sponge table: id = ((d*5+g)*256 + t)*4 + w
        int w  = id & 3;
        int t  = (id >> 2) & 255;
        int dg = id >> 10;
        int d = dg / 5, g = dg - 5 * d;
        int pA1 = 2 * (t & 127) + (t >> 7);
        int pair = (w == 0) ? pA1 : (w == 1) ? (pA1 + 256)
                 : (w == 2) ? (2 * pA1) : (2 * pA1 + 1);
        int st = 2 * g + (w >> 1);
        float a = angles[(d * 10 + st) * 512 + pair];
        float s, c; sincosf(a, &s, &c);
        ws[FTAB_OFF + 2 * id]     = c;
        ws[FTAB_OFF + 2 * id + 1] = s;
    } else if (id < 40960 + 18432) {
        int idb = id - 40960;                  // st*1536 + p
        float a = bf_angles[idb];
        float s, c; sincosf(a, &s, &c);
        ws[BFT_OFF + 2 * idb]     = c;
        ws[BFT_OFF + 2 * idb + 1] = s;
    } else if (id < 40960 + 18432 + 2048) {
        int ida = id - 59392;                  // d*256 + k
        float cu = act_curv[ida];
        float c  = 0.5f * (cu + sqrtf(cu * cu + 1.0f));
        ((float4*)(ws + ACT4_OFF))[ida] =
            make_float4(act_bias[ida], c, 1.0f / c, 0.0f);
    }
}

// ---------------- precompute: compacted mem slot allocation (2304 phys slots) ------
// birth at depth d, slot j: j<256 (d>0) -> fresh 256+256d+j ; d==0 -> j ;
// j>=256 -> inherit phys of its recall victim recall_idx[d-1][j-256] (<=8-hop chain)
__global__ void phys_precompute(const int* __restrict__ recall_idx,
                                const int* __restrict__ out_mem_idx,
                                float* __restrict__ ws) {
    __shared__ int physL[4096];
    int t = threadIdx.x;   // 1024 threads, 1 block
    for (int q = 0; q < 4; ++q) {
        int v = t + q * 1024;
        int p;
        for (;;) {
            int d = v >> 9, j = v & 511;
            if (d == 0)  { p = j; break; }
            if (j < 256) { p = 256 + d * 256 + j; break; }
            v = recall_idx[(d - 1) * 256 + (j - 256)];
        }
        physL[t + q * 1024] = p;
        ((int*)(ws + PHYS_OFF))[t + q * 1024] = p;
    }
    __syncthreads();
    for (int q = 0; q < 2; ++q) {
        int i = t + q * 1024;
        ((int*)(ws + PHYSR_OFF))[i] = physL[recall_idx[i]];
        ((int*)(ws + PHYSO_OFF))[i] = physL[out_mem_idx[i]];
    }
}

__device__ __forceinline__ float actf(float x, float c, float ic) {
    const float is2 = 0.70710678118654752f;
    float tt = 0.78539816339744831f * ic;
    float y0 = is2 * ic;
    float y1 = (is2 - 1.0f) * ic;
    float mid = ic * (is2 - __cosf(0.78539816339744831f + c * x));
    return x > tt ? (y0 + (x - tt)) : (x < -tt ? y1 : mid);
}

// ---------------- main kernel ------------------------------------------------------
__launch_bounds__(256, 8)
__global__ void sponge_kernel(const float* __restrict__ X,
                              const float* __restrict__ scales,
                              const float* __restrict__ ws,
                              float* __restrict__ out) {
    __shared__ float lds[4352];          // 17408 B -> 8 blocks/CU
    float* memb = lds;                   // [0,2304)  compacted mem
    float* pb0  = lds + 2304;            // [2304,3328)
    float* pb1  = lds + 3328;            // [3328,4352)
    const int t   = threadIdx.x;
    const int row = blockIdx.x;

    const float* ftab = ws + FTAB_OFF;
    const float* bft  = ws + BFT_OFF;
    const float4* act4 = (const float4*)(ws + ACT4_OFF);
    const int* phys  = (const int*)(ws + PHYS_OFF);
    const int* physr = (const int*)(ws + PHYSR_OFF);
    const int* physo = (const int*)(ws + PHYSO_OFF);

    const int tl = t & 127, th = t >> 7;
    const int b  = tl + th * 512;        // holding base: {b,b+128,b+256,b+384}
    const int a  = 2 * tl + th;          // post-A base / write base

    // ---- init holdings: h_i = X[row][b+128i] * scales[b+128i] ----
    float h0, h1, h2, h3;
    {
        const float* Xr = X + (size_t)row * 1024;
        h0 = Xr[b]       * scales[b];
        h1 = Xr[b + 128] * scales[b + 128];
        h2 = Xr[b + 256] * scales[b + 256];
        h3 = Xr[b + 384] * scales[b + 384];
    }

    float* wbuf = pb0;
    float* rbuf = pb1;

    for (int d = 0; d < DEPTH; ++d) {
        for (int g = 0; g < 5; ++g) {
            const float4* ft = (const float4*)(ftab + (size_t)((d * 5 + g) * 256 + t) * 8);
            float4 csA = ft[0];   // (cA1,sA1,cA2,sA2) pairs (a, a+256)
            float4 csB = ft[1];   // (cB1,sB1,cB2,sB2) pairs (2a, 2a+1)
            // stage A (register-only)
            float g0 =  csA.x * h0 + csA.y * h2;
            float g2 = -csA.y * h0 + csA.x * h2;
            float g1 =  csA.z * h1 + csA.w * h3;
            float g3 = -csA.w * h1 + csA.z * h3;
            // stage B (register-only)
            float f0 =  csB.x * g0 + csB.y * g1;
            float f2 = -csB.y * g0 + csB.x * g1;
            float f1 =  csB.z * g2 + csB.w * g3;
            float f3 = -csB.w * g2 + csB.z * g3;
            // outputs live at {2a, 2a+1, 2a+512, 2a+513}
            ((float2*)(wbuf + 2 * a))[0]       = make_float2(f0, f1);
            ((float2*)(wbuf + 2 * a + 512))[0] = make_float2(f2, f3);
            { float* tmp = wbuf; wbuf = rbuf; rbuf = tmp; }   // rbuf = just written
            __syncthreads();
            if (g < 4) {   // exchange to {b,b+128,b+256,b+384} layout
                h0 = rbuf[b];
                h1 = rbuf[b + 128];
                h2 = rbuf[b + 256];
                h3 = rbuf[b + 384];
            }
        }
        // ---- repack (z = rbuf) ----
        const float* z = rbuf;
        {   // mem store: slots d*512 + {2t,2t+1}
            float2 mv = ((const float2*)(z + 2 * t))[0];
            int2  pm  = ((const int2*)(phys + d * 512))[t];
            memb[pm.x] = mv.x;
            memb[pm.y] = mv.y;
        }
        int r0 = 0, r1 = 0;
        if (t < 128) {
            // act region: holdings {t,t+128,t+256,t+384}, all parity t&1, k = v>>1
            int k0 = t >> 1;
            float x10 = z[512 + k0];
            float x11 = z[512 + k0 + 64];
            float x12 = z[512 + k0 + 128];
            float x13 = z[512 + k0 + 192];
            float4 a0 = act4[d * 256 + k0];
            float4 a1 = act4[d * 256 + k0 + 64];
            float4 a2 = act4[d * 256 + k0 + 128];
            float4 a3 = act4[d * 256 + k0 + 192];
            float sgn = (t & 1) ? -1.0f : 1.0f;
            h0 = actf(sgn * (x10 + a0.x), a0.y, a0.z);
            h1 = actf(sgn * (x11 + a1.x), a1.y, a1.z);
            h2 = actf(sgn * (x12 + a2.x), a2.y, a2.z);
            h3 = actf(sgn * (x13 + a3.x), a3.y, a3.z);
        } else {
            // keep + recall region: holdings {512+u,640+u,768+u,896+u}
            int u = t - 128;
            h0 = z[768 + u];
            h1 = z[896 + u];
            r0 = physr[d * 256 + u];
            r1 = physr[d * 256 + u + 128];
        }
        __syncthreads();                 // mem writes visible
        if (t >= 128) {
            h2 = memb[r0];
            h3 = memb[r1];
        }
    }

    // ---- build pre[0:3072) in lds: [mem gather 2048 | sponge 1024] ----
    float gv[8];
#pragma unroll
    for (int q = 0; q < 8; ++q) gv[q] = memb[physo[q * 256 + t]];
    __syncthreads();                     // all memb/z reads done before overwrite
#pragma unroll
    for (int q = 0; q < 8; ++q) lds[q * 256 + t] = gv[q];
    lds[2048 + b]       = h0;
    lds[2048 + b + 128] = h1;
    lds[2048 + b + 256] = h2;
    lds[2048 + b + 384] = h3;
    __syncthreads();

    float* buf = lds;

    // ---- stages 0..2: full 3072-wide, in place ----
    for (int s = 0; s < 3; ++s) {
        const float* tbs = bft + s * 3072;
        float  r[12];
        float4 csg[3];
#pragma unroll
        for (int gi = 0; gi < 3; ++gi) {
            csg[gi] = *(const float4*)(tbs + 4 * t + 1024 * gi);
            r[4 * gi + 0] = buf[t + 256 * gi];
            r[4 * gi + 1] = buf[t + 256 * gi + 768];
            r[4 * gi + 2] = buf[t + 256 * gi + 1536];
            r[4 * gi + 3] = buf[t + 256 * gi + 2304];
        }
        __syncthreads();
#pragma unroll
        for (int gi = 0; gi < 3; ++gi) {
            int j0 = 2 * t + 512 * gi;
            float4 cs = csg[gi];
            float av = r[4 * gi], bv = r[4 * gi + 1], cv = r[4 * gi + 2], ev = r[4 * gi + 3];
            ((float2*)(buf + j0))[0] =
                make_float2( cs.x * av + cs.y * bv,  cs.z * cv + cs.w * ev);
            ((float2*)(buf + 1536 + j0))[0] =
                make_float2(-cs.y * av + cs.x * bv, -cs.w * cv + cs.z * ev);
        }
        __syncthreads();
    }

    // ---- stages 3..10: pruned to the 512 needed rotation-pairs ----
#pragma unroll
    for (int s = 3; s < 11; ++s) {
        const float* tbs = bft + s * 3072;
        const int k  = 10 - s;
        const int M  = 768 >> k;
        const int Wl = 8 - k;
        const int Wm = (256 >> k) - 1;
        float  X1[2], X2[2];
        float2 cs2[2];
        int    pp[2];
#pragma unroll
        for (int u = 0; u < 2; ++u) {
            int i = t + 256 * u;
            int p = ((i >> Wl) * M) + (i & Wm);
            pp[u]  = p;
            cs2[u] = *(const float2*)(tbs + 2 * p);
            X1[u] = buf[(p >> 1) + (p & 1) * 1536];
            X2[u] = buf[768 + (p >> 1) + (p & 1) * 1536];
        }
        __syncthreads();
#pragma unroll
        for (int u = 0; u < 2; ++u) {
            buf[pp[u]]        =  cs2[u].x * X1[u] + cs2[u].y * X2[u];
            buf[pp[u] + 1536] = -cs2[u].y * X1[u] + cs2[u].x * X2[u];
        }
        __syncthreads();
    }

    // ---- stage 11 fused into the output store ----
    {
        const float* tbs = bft + 11 * 3072;
        float4 cs = *(const float4*)(tbs + 4 * t);
        float av = buf[t], bv = buf[768 + t], cv = buf[1536 + t], ev = buf[2304 + t];
        ((float2*)(out + (size_t)row * 512))[t] =
            make_float2(cs.x * av + cs.y * bv, cs.z * cv + cs.w * ev);
    }
}

extern "C" void kernel_launch(void* const* d_in, const int* in_sizes, int n_in,
                              void* d_out, int out_size, void* d_ws, size_t ws_size,
                              hipStream_t stream) {
    const float* X          = (const float*)d_in[0];
    const float* scales     = (const float*)d_in[1];
    const float* angles     = (const float*)d_in[2];
    const float* act_bias   = (const float*)d_in[3];
    // d_in[4] act_activation — unused by the reference
    const float* act_curv   = (const float*)d_in[5];
    const float* bf_angles  = (const float*)d_in[6];
    // d_in[7] shuffle_perm — structural perfect shuffle, hardcoded
    const int*   recall_idx  = (const int*)d_in[8];
    const int*   out_mem_idx = (const int*)d_in[9];
    // d_in[10] bf_perm — structural perfect shuffle, hardcoded

    float* ws = (float*)d_ws;   // 540672 bytes used

    tab_precompute<<<240, 256, 0, stream>>>(angles, bf_angles, act_bias, act_curv, ws);
    phys_precompute<<<1, 1024, 0, stream>>>(recall_idx, out_mem_idx, ws);
    sponge_kernel<<<NB, 256, 0, stream>>>(X, scales, ws, (float*)d_out);
}